// Round 11
// baseline (262.080 us; speedup 1.0000x reference)
//
#include <hip/hip_runtime.h>
#include <math.h>
#include <float.h>

#define B_ 64
#define S_ 512
#define N_ 256
#define P_ 96
#define D_ 64
#define WIN_ 24
#define L_ 488   // S_ - WIN_
#define MID_ 7
#define PB_ (P_*B_)   // 6144

typedef unsigned short u16;
typedef __attribute__((ext_vector_type(4))) float floatx4;
typedef __attribute__((ext_vector_type(8))) short bf16x8;
#define MFMA16(a,b,c) __builtin_amdgcn_mfma_f32_16x16x32_bf16(a,b,c,0,0,0)

// workspace layout (BYTE offsets)
#define OFF_XST  ((size_t)0)                 // XsT bf16 [B][N][L]  15,990,784 B
#define OFF_TRT  ((size_t)15990784)          // trT bf16 [N][B][L]  15,990,784 B
#define OFF_WSEB ((size_t)31981568)          // season weights bf16 [B][P][L] 5,996,544 B
#define OFF_WM   ((size_t)37978112)          // mid weights bf16 [B][MID][L] 437,248 B
// trend partials bf16 [N][P][B] (3,145,728 B) alias WSEB; consumed by
// k_reduce_trend BEFORE k_scores_se writes WSEB (stream-sequential).
#define OFF_PART OFF_WSEB

__device__ inline u16 f2bf(float f) {
    union { float f; unsigned u; } v; v.f = f;
    unsigned r = v.u + 0x7FFFu + ((v.u >> 16) & 1u);
    return (u16)(r >> 16);
}
__device__ inline float bf2f(u16 u) {
    union { unsigned u; float f; } v; v.u = ((unsigned)u) << 16;
    return v.f;
}
// time2vec element d of embed at time t (d==0 linear, else sin)
__device__ inline float t2v(float t, int d, float w0v, float b0v,
                            const float* __restrict__ Wp,
                            const float* __restrict__ Bp) {
    return (d == 0) ? (t * w0v + b0v) : sinf(t * Wp[d - 1] + Bp[d - 1]);
}

// ---------------- Kernel 1: rolling-mean trend + season ----------------
// grid (B, 16 l-tiles of 32), block 256 (thread = n). Emits XsT [B][N][L]
// and trT [N][B][L] via LDS transpose (XSB natural-layout copy eliminated).
__global__ __launch_bounds__(256) void k_trend(const float* __restrict__ X,
                                               u16* __restrict__ XST,
                                               u16* __restrict__ TRT) {
    int b = blockIdx.x, tile = blockIdx.y, n = threadIdx.x;
    __shared__ u16 tr_tile[256][34];
    __shared__ u16 xs_tile[256][34];
    const float* Xb = X + (size_t)b * S_ * N_ + n;
    int l0 = tile * 32;
    int cur = L_ - l0; if (cur > 32) cur = 32;    // 32 or 8 (tail)
    int s1 = WIN_ + l0;
    float wsum = 0.f;
    for (int s = s1 - WIN_; s < s1; ++s) wsum += Xb[(size_t)s * N_];
    for (int i = 0; i < cur; ++i) {
        int s = s1 + i;
        float xv = Xb[(size_t)s * N_];
        wsum += xv - Xb[(size_t)(s - WIN_) * N_];
        float tr = wsum * (1.f / WIN_);
        tr_tile[n][i] = f2bf(tr);
        xs_tile[n][i] = f2bf(xv - tr);
    }
    __syncthreads();
    int wv = threadIdx.x >> 6, lane = threadIdx.x & 63;
    int half = lane >> 5, c = lane & 31;          // 2 rows per instruction
    if (c < cur) {
        for (int it = 0; it < 32; ++it) {
            int r = it * 8 + wv * 2 + half;
            TRT[(size_t)r * (B_ * L_) + (size_t)b * L_ + l0 + c] = tr_tile[r][c];
            XST[((size_t)b * N_ + r) * L_ + l0 + c] = xs_tile[r][c];
        }
    }
}

// ------- Kernel 2: trend GEMM via MFMA, p-split x2, bias folded, ----------
// bf16 partials. grid (N_, 2). C[48 p][64 b] = Wn . trTn^T + bt.
__global__ __launch_bounds__(256) void k_trend_gemm(const float* __restrict__ Wt_g,
                                                    const float* __restrict__ bt,
                                                    const u16* __restrict__ TRT,
                                                    u16* __restrict__ part) {
    int n = blockIdx.x, ph = blockIdx.y, tid = threadIdx.x;
    int lane = tid & 63, wv = tid >> 6;
    int fr = lane & 15, quad = lane >> 4;
    __shared__ __align__(16) char smem_raw[12288];
    u16* Al = (u16*)smem_raw;            // [48][40] bf16
    u16* Bl = Al + 48 * 40;              // [64][40] bf16
    u16* Cst = (u16*)smem_raw;           // epilogue [48][64] bf16
    const float* Wn = Wt_g + ((size_t)n * P_ + (size_t)ph * 48) * L_;
    const u16* Tn = TRT + (size_t)n * (B_ * L_);
    floatx4 acc[3];
#pragma unroll
    for (int j = 0; j < 3; ++j) acc[j] = (floatx4){0.f, 0.f, 0.f, 0.f};
    float4 wr[2];
    uint4 br;

    auto fetch = [&](int c) {
        int k0 = c * 32, cur = L_ - k0;
#pragma unroll
        for (int t = 0; t < 2; ++t) {
            int u = tid + t * 256;                // W: 48*8 = 384 float4
            wr[t] = make_float4(0.f, 0.f, 0.f, 0.f);
            if (u < 384) {
                int row = u >> 3, c4 = (u & 7) * 4;
                if (c4 < cur) wr[t] = *(const float4*)&Wn[(size_t)row * L_ + k0 + c4];
            }
        }
        int brow = tid >> 2, c8 = (tid & 3) * 8;  // B: 64*4 = 256 uint4
        br = (c8 < cur) ? *(const uint4*)&Tn[(size_t)brow * L_ + k0 + c8]
                        : make_uint4(0u, 0u, 0u, 0u);
    };
    auto stage = [&]() {
#pragma unroll
        for (int t = 0; t < 2; ++t) {
            int u = tid + t * 256;
            if (u < 384) {
                int row = u >> 3, c4 = (u & 7) * 4;
                ushort4 pk;
                pk.x = f2bf(wr[t].x); pk.y = f2bf(wr[t].y);
                pk.z = f2bf(wr[t].z); pk.w = f2bf(wr[t].w);
                *(ushort4*)&Al[row * 40 + c4] = pk;
            }
        }
        int brow = tid >> 2, c8 = (tid & 3) * 8;
        *(uint4*)&Bl[brow * 40 + c8] = br;
    };
    auto compute = [&]() {
        bf16x8 bfr = *(const bf16x8*)&Bl[(wv * 16 + fr) * 40 + quad * 8];
#pragma unroll
        for (int j = 0; j < 3; ++j) {
            bf16x8 afr = *(const bf16x8*)&Al[(j * 16 + fr) * 40 + quad * 8];
            acc[j] = MFMA16(afr, bfr, acc[j]);
        }
    };

    fetch(0); stage();
    for (int c = 1; c < 16; ++c) {
        fetch(c);
        __syncthreads();
        compute();
        __syncthreads();
        stage();
    }
    __syncthreads();
    compute();

    __syncthreads();
#pragma unroll
    for (int j = 0; j < 3; ++j)
#pragma unroll
        for (int r = 0; r < 4; ++r) {
            int p = j * 16 + quad * 4 + r;
            float bias = bt[(size_t)(ph * 48 + p) * N_ + n];
            Cst[p * 64 + wv * 16 + fr] = f2bf(acc[j][r] + bias);
        }
    __syncthreads();
    u16* dstp = part + (size_t)n * PB_ + (size_t)ph * 48 * B_;
    for (int u = tid; u < 384; u += 256)          // 3072 u16 = 384 uint4
        *(uint4*)&dstp[u * 8] = *(const uint4*)&Cst[u * 8];
}

// ------- Kernel 3: transpose bf16 partial[n][p][b] -> fp32 out0 [b][p][n] --
__global__ __launch_bounds__(256) void k_reduce_trend(const u16* __restrict__ part,
                                                      float* __restrict__ out0) {
    int nt = blockIdx.x, p = blockIdx.y, tid = threadIdx.x;
    __shared__ float t[32][65];
    int n0 = nt * 32;
    for (int idx = tid; idx < 512; idx += 256) {
        int i = idx >> 4, j4 = (idx & 15) * 4;
        ushort4 v = *(const ushort4*)&part[(size_t)(n0 + i) * PB_ + p * 64 + j4];
        t[i][j4 + 0] = bf2f(v.x); t[i][j4 + 1] = bf2f(v.y);
        t[i][j4 + 2] = bf2f(v.z); t[i][j4 + 3] = bf2f(v.w);
    }
    __syncthreads();
    for (int idx = tid; idx < 2048; idx += 256) {
        int bb = idx >> 5, nl = idx & 31;
        out0[((size_t)bb * P_ + p) * N_ + n0 + nl] = t[nl][bb];
    }
}

// ------- Kernel 4: FUSED scores + softmax -> bf16 weights. ----------------
// grid (B, 8 q-tiles of 12), block 256. Each block owns FULL score rows:
// loops k-chunks of 64, regenerating the ET time2vec tile in LDS (sinf is
// ~free in aggregate), scores fp32 in LDS, per-wave softmax (wave qg only
// touches rows it wrote - no cross-wave reduction), bf16 weights out.
// qt==0 blocks also carry the 7 masked mid rows (same ET tiles).
// fp32 scores mandatory (O(2500), exp-sensitive - round 6 lesson).
__global__ __launch_bounds__(256) void k_scores_se(const float* __restrict__ T,
                                                   const float* __restrict__ w0,
                                                   const float* __restrict__ b0,
                                                   const float* __restrict__ Wp,
                                                   const float* __restrict__ Bp,
                                                   u16* __restrict__ WSEB,
                                                   u16* __restrict__ WM) {
    int b = blockIdx.x, qt = blockIdx.y, tid = threadIdx.x;
    int q0 = qt * 12;
    __shared__ float ENl[12][68];
    __shared__ float ETl[64][68];
    __shared__ float qv[7][68];
    __shared__ float Sc[12][496];
    __shared__ float Scm[7][496];
    float w0v = w0[0], b0v = b0[0];
    const float* Tb = T + (size_t)b * S_ + WIN_;
    float Tlast = T[(size_t)b * S_ + (S_ - 1)];
    bool domid = (qt == 0);
    for (int idx = tid; idx < 12 * 64; idx += 256) {
        int lr = idx >> 6, d = idx & 63;
        ENl[lr][d] = t2v(Tlast + (float)(q0 + lr + 1), d, w0v, b0v, Wp, Bp);
    }
    if (domid) {
        for (int idx = tid; idx < 7 * 64; idx += 256) {
            int q = idx >> 6, d = idx & 63;
            qv[q][d] = t2v(Tb[L_ - MID_ + q], d, w0v, b0v, Wp, Bp);
        }
    }
    int klane = tid & 63, qg = tid >> 6;          // qg: wave id, owns 3 rows
    for (int kt = 0; kt < 8; ++kt) {
        int k0 = kt * 64;
        __syncthreads();                          // ETl reuse from prev iter
        for (int idx = tid; idx < 4096; idx += 256) {
            int kk = idx >> 6, d = idx & 63;
            int k = k0 + kk;
            ETl[kk][d] = (k < L_) ? t2v(Tb[k], d, w0v, b0v, Wp, Bp) : 0.f;
        }
        __syncthreads();
        float a0 = 0.f, a1 = 0.f, a2 = 0.f, m0 = 0.f, m1 = 0.f;
        for (int d = 0; d < 64; d += 4) {
            float4 e  = *(const float4*)&ETl[klane][d];
            float4 x0 = *(const float4*)&ENl[qg * 3 + 0][d];
            float4 x1 = *(const float4*)&ENl[qg * 3 + 1][d];
            float4 x2 = *(const float4*)&ENl[qg * 3 + 2][d];
            a0 += e.x * x0.x + e.y * x0.y + e.z * x0.z + e.w * x0.w;
            a1 += e.x * x1.x + e.y * x1.y + e.z * x1.z + e.w * x1.w;
            a2 += e.x * x2.x + e.y * x2.y + e.z * x2.z + e.w * x2.w;
            if (domid) {
                float4 y0 = *(const float4*)&qv[qg][d];
                m0 += e.x * y0.x + e.y * y0.y + e.z * y0.z + e.w * y0.w;
                if (qg + 4 < 7) {
                    float4 y1 = *(const float4*)&qv[qg + 4][d];
                    m1 += e.x * y1.x + e.y * y1.y + e.z * y1.z + e.w * y1.w;
                }
            }
        }
        int k = k0 + klane;
        if (k < L_) {
            Sc[qg * 3 + 0][k] = a0 * 0.125f;
            Sc[qg * 3 + 1][k] = a1 * 0.125f;
            Sc[qg * 3 + 2][k] = a2 * 0.125f;
            if (domid) {
                Scm[qg][k] = (k < L_ - MID_ + qg) ? m0 * 0.125f : -FLT_MAX;
                if (qg + 4 < 7)
                    Scm[qg + 4][k] = (k < L_ - MID_ + qg + 4) ? m1 * 0.125f : -FLT_MAX;
            }
        }
    }
    // per-wave softmax over own rows (same wave wrote them)
    for (int j = 0; j < 3; ++j) {
        int lr = qg * 3 + j;
        float v[8], m = -FLT_MAX;
#pragma unroll
        for (int i = 0; i < 8; ++i) {
            int idx = i * 64 + klane;
            v[i] = (idx < L_) ? Sc[lr][idx] : -FLT_MAX;
            m = fmaxf(m, v[i]);
        }
        for (int off = 32; off; off >>= 1) m = fmaxf(m, __shfl_xor(m, off));
        float s = 0.f;
#pragma unroll
        for (int i = 0; i < 8; ++i) { float e = expf(v[i] - m); v[i] = e; s += e; }
        for (int off = 32; off; off >>= 1) s += __shfl_xor(s, off);
        float inv = 1.f / s;
        u16* outp = WSEB + ((size_t)b * P_ + q0 + lr) * L_;
#pragma unroll
        for (int i = 0; i < 8; ++i) {
            int idx = i * 64 + klane;
            if (idx < L_) outp[idx] = f2bf(v[i] * inv);
        }
    }
    if (domid) {
        for (int j = 0; j < 2; ++j) {
            int lr = qg + 4 * j;
            if (lr < 7) {
                float v[8], m = -FLT_MAX;
#pragma unroll
                for (int i = 0; i < 8; ++i) {
                    int idx = i * 64 + klane;
                    v[i] = (idx < L_) ? Scm[lr][idx] : -FLT_MAX;
                    m = fmaxf(m, v[i]);
                }
                for (int off = 32; off; off >>= 1) m = fmaxf(m, __shfl_xor(m, off));
                float s = 0.f;
#pragma unroll
                for (int i = 0; i < 8; ++i) { float e = expf(v[i] - m); v[i] = e; s += e; }
                for (int off = 32; off; off >>= 1) s += __shfl_xor(s, off);
                float inv = 1.f / s;
                u16* outp = WM + ((size_t)b * MID_ + lr) * L_;
#pragma unroll
                for (int i = 0; i < 8; ++i) {
                    int idx = i * 64 + klane;
                    if (idx < L_) outp[idx] = f2bf(v[i] * inv);
                }
            }
        }
    }
}

// ------- Kernel 5: season PV via MFMA, q-split x2. grid (B, 4, 2). --------
__global__ __launch_bounds__(256) void k_season_pv(const u16* __restrict__ WSEB,
                                                   const u16* __restrict__ XST,
                                                   float* __restrict__ out0) {
    int b = blockIdx.x, nt = blockIdx.y, qh = blockIdx.z, tid = threadIdx.x;
    int lane = tid & 63, wv = tid >> 6;
    int fr = lane & 15, quad = lane >> 4;
    __shared__ __align__(16) char smem_raw[12288];
    u16* Al = (u16*)smem_raw;            // Wse [48][40]
    u16* Bl = Al + 48 * 40;              // XsT [64][40]
    float* Cst = (float*)smem_raw;       // [48][64]
    const u16* Wa = WSEB + ((size_t)b * P_ + (size_t)qh * 48) * L_;
    const u16* Xb = XST + ((size_t)b * N_ + nt * 64) * L_;
    floatx4 acc[3];
#pragma unroll
    for (int j = 0; j < 3; ++j) acc[j] = (floatx4){0.f, 0.f, 0.f, 0.f};
    uint4 ar, br;

    auto fetch = [&](int c) {
        int k0 = c * 32, cur = L_ - k0;
        ar = make_uint4(0u, 0u, 0u, 0u);
        if (tid < 192) {
            int row = tid >> 2, c8 = (tid & 3) * 8;
            if (c8 < cur) ar = *(const uint4*)&Wa[(size_t)row * L_ + k0 + c8];
        }
        int brow = tid >> 2, c8 = (tid & 3) * 8;
        br = (c8 < cur) ? *(const uint4*)&Xb[(size_t)brow * L_ + k0 + c8]
                        : make_uint4(0u, 0u, 0u, 0u);
    };
    auto stage = [&]() {
        if (tid < 192) {
            int row = tid >> 2, c8 = (tid & 3) * 8;
            *(uint4*)&Al[row * 40 + c8] = ar;
        }
        int brow = tid >> 2, c8 = (tid & 3) * 8;
        *(uint4*)&Bl[brow * 40 + c8] = br;
    };
    auto compute = [&]() {
        bf16x8 bfr = *(const bf16x8*)&Bl[(wv * 16 + fr) * 40 + quad * 8];
#pragma unroll
        for (int j = 0; j < 3; ++j) {
            bf16x8 afr = *(const bf16x8*)&Al[(j * 16 + fr) * 40 + quad * 8];
            acc[j] = MFMA16(afr, bfr, acc[j]);
        }
    };

    fetch(0); stage();
    for (int c = 1; c < 16; ++c) {
        fetch(c);
        __syncthreads();
        compute();
        __syncthreads();
        stage();
    }
    __syncthreads();
    compute();

    __syncthreads();
#pragma unroll
    for (int j = 0; j < 3; ++j)
#pragma unroll
        for (int r = 0; r < 4; ++r)
            Cst[(j * 16 + quad * 4 + r) * 64 + wv * 16 + fr] = acc[j][r];
    __syncthreads();
    float* o = out0 + (size_t)b * P_ * N_ + nt * 64;
    for (int u = tid; u < 768; u += 256) {
        int pl = u >> 4, c4 = (u & 15) * 4;
        float4* op = (float4*)&o[(size_t)(qh * 48 + pl) * N_ + c4];
        float4 pv = *op;
        const float* cs = &Cst[pl * 64 + c4];
        pv.x += cs[0]; pv.y += cs[1]; pv.z += cs[2]; pv.w += cs[3];
        *op = pv;
    }
}

// ------- Kernel 6: mid PV from XsT + bf16 weights. grid (B, 8), block 256 --
__global__ __launch_bounds__(256) void k_mid_pv(const u16* __restrict__ XST,
                                                const u16* __restrict__ WM,
                                                float* __restrict__ out1) {
    int b = blockIdx.x, nt = blockIdx.y, tid = threadIdx.x;
    int nl = tid & 31, ks = tid >> 5;   // 8 k-slices of 61
    __shared__ float wl[7 * L_];
    __shared__ float part[8][7][33];
    const u16* WMb = WM + (size_t)b * MID_ * L_;
    for (int idx = tid; idx < 7 * L_; idx += 256) wl[idx] = bf2f(WMb[idx]);
    __syncthreads();
    const u16* xrow = XST + ((size_t)b * N_ + nt * 32 + nl) * L_;
    float acc[7] = {};
    int kbeg = ks * 61, kend = kbeg + 61;
    for (int k = kbeg; k < kend; ++k) {
        float xv = bf2f(xrow[k]);
#pragma unroll
        for (int q = 0; q < 7; ++q) acc[q] += wl[q * L_ + k] * xv;
    }
#pragma unroll
    for (int q = 0; q < 7; ++q) part[ks][q][nl] = acc[q];
    __syncthreads();
    if (ks == 0) {
#pragma unroll
        for (int q = 0; q < 7; ++q) {
            float v = 0.f;
#pragma unroll
            for (int s = 0; s < 8; ++s) v += part[s][q][nl];
            out1[((size_t)b * MID_ + q) * N_ + nt * 32 + nl] = v;
        }
    }
}

extern "C" void kernel_launch(void* const* d_in, const int* in_sizes, int n_in,
                              void* d_out, int out_size, void* d_ws, size_t ws_size,
                              hipStream_t stream) {
    (void)in_sizes; (void)n_in; (void)out_size; (void)ws_size;
    const float* X  = (const float*)d_in[0];
    const float* T  = (const float*)d_in[1];
    const float* Wt = (const float*)d_in[2];
    const float* bt = (const float*)d_in[3];
    const float* w0 = (const float*)d_in[4];
    const float* b0 = (const float*)d_in[5];
    const float* Wp = (const float*)d_in[6];
    const float* Bp = (const float*)d_in[7];
    float* out = (float*)d_out;
    char* w8 = (char*)d_ws;
    float* out1 = out + (size_t)B_ * P_ * N_;

    u16* XST  = (u16*)(w8 + OFF_XST);
    u16* TRT  = (u16*)(w8 + OFF_TRT);
    u16* WSEB = (u16*)(w8 + OFF_WSEB);
    u16* WM   = (u16*)(w8 + OFF_WM);
    u16* PART = (u16*)(w8 + OFF_PART);

    hipLaunchKernelGGL(k_trend, dim3(B_, 16), dim3(256), 0, stream, X, XST, TRT);
    hipLaunchKernelGGL(k_trend_gemm, dim3(N_, 2), dim3(256), 0, stream, Wt, bt, TRT, PART);
    hipLaunchKernelGGL(k_reduce_trend, dim3(8, 96), dim3(256), 0, stream, PART, out);
    hipLaunchKernelGGL(k_scores_se, dim3(B_, 8), dim3(256), 0, stream,
                       T, w0, b0, Wp, Bp, WSEB, WM);
    hipLaunchKernelGGL(k_season_pv, dim3(B_, 4, 2), dim3(256), 0, stream, WSEB, XST, out);
    hipLaunchKernelGGL(k_mid_pv, dim3(B_, 8), dim3(256), 0, stream, XST, WM, out1);
}

// Round 12
// 198.849 us; speedup vs baseline: 1.3180x; 1.3180x over previous
//
#include <hip/hip_runtime.h>
#include <math.h>
#include <float.h>

#define B_ 64
#define S_ 512
#define N_ 256
#define P_ 96
#define D_ 64
#define WIN_ 24
#define L_ 488   // S_ - WIN_
#define MID_ 7
#define PB_ (P_*B_)   // 6144

typedef unsigned short u16;
typedef __attribute__((ext_vector_type(4))) float floatx4;
typedef __attribute__((ext_vector_type(8))) short bf16x8;
#define MFMA16(a,b,c) __builtin_amdgcn_mfma_f32_16x16x32_bf16(a,b,c,0,0,0)

// workspace layout (BYTE offsets)
#define OFF_XST  ((size_t)0)                 // XsT bf16 [B][N][L]
#define OFF_TRT  ((size_t)15990784)          // trT bf16 [N][B][L]
#define OFF_WSE  ((size_t)31981568)          // season scores fp32 [B][P][L]
#define OFF_WSEB ((size_t)43974656)          // season weights bf16 [B][P][L]
#define OFF_WM   ((size_t)49971200)          // mid scores fp32 [B][MID][L]
// trend partials bf16 [N][P][B] (3.1 MB) alias WSE; consumed by
// k_reduce_trend BEFORE k_scores writes WSE.
#define OFF_PART OFF_WSE

__device__ inline u16 f2bf(float f) {
    union { float f; unsigned u; } v; v.f = f;
    unsigned r = v.u + 0x7FFFu + ((v.u >> 16) & 1u);
    return (u16)(r >> 16);
}
__device__ inline float bf2f(u16 u) {
    union { unsigned u; float f; } v; v.u = ((unsigned)u) << 16;
    return v.f;
}
// time2vec element d of embed at time t (d==0 linear, else sin)
__device__ inline float t2v(float t, int d, float w0v, float b0v,
                            const float* __restrict__ Wp,
                            const float* __restrict__ Bp) {
    return (d == 0) ? (t * w0v + b0v) : sinf(t * Wp[d - 1] + Bp[d - 1]);
}

// ---------------- Kernel 1: rolling-mean trend + season ----------------
// grid (B, 16 l-tiles of 32), block 256 (thread = n). Emits XsT [B][N][L]
// and trT [N][B][L] via LDS transpose. (XSB copy eliminated — mid_pv
// reads XsT rows, L1-resident.)
__global__ __launch_bounds__(256) void k_trend(const float* __restrict__ X,
                                               u16* __restrict__ XST,
                                               u16* __restrict__ TRT) {
    int b = blockIdx.x, tile = blockIdx.y, n = threadIdx.x;
    __shared__ u16 tr_tile[256][34];
    __shared__ u16 xs_tile[256][34];
    const float* Xb = X + (size_t)b * S_ * N_ + n;
    int l0 = tile * 32;
    int cur = L_ - l0; if (cur > 32) cur = 32;    // 32 or 8 (tail)
    int s1 = WIN_ + l0;
    float wsum = 0.f;
    for (int s = s1 - WIN_; s < s1; ++s) wsum += Xb[(size_t)s * N_];
    for (int i = 0; i < cur; ++i) {
        int s = s1 + i;
        float xv = Xb[(size_t)s * N_];
        wsum += xv - Xb[(size_t)(s - WIN_) * N_];
        float tr = wsum * (1.f / WIN_);
        tr_tile[n][i] = f2bf(tr);
        xs_tile[n][i] = f2bf(xv - tr);
    }
    __syncthreads();
    int wv = threadIdx.x >> 6, lane = threadIdx.x & 63;
    int half = lane >> 5, c = lane & 31;          // 2 rows per instruction
    if (c < cur) {
        for (int it = 0; it < 32; ++it) {
            int r = it * 8 + wv * 2 + half;
            TRT[(size_t)r * (B_ * L_) + (size_t)b * L_ + l0 + c] = tr_tile[r][c];
            XST[((size_t)b * N_ + r) * L_ + l0 + c] = xs_tile[r][c];
        }
    }
}

// ------- Kernel 2: trend GEMM via MFMA, p-split x2, bias folded, ----------
// bf16 partials. grid (N_, 2). C[48 p][64 b] = Wn . trTn^T + bt.
__global__ __launch_bounds__(256) void k_trend_gemm(const float* __restrict__ Wt_g,
                                                    const float* __restrict__ bt,
                                                    const u16* __restrict__ TRT,
                                                    u16* __restrict__ part) {
    int n = blockIdx.x, ph = blockIdx.y, tid = threadIdx.x;
    int lane = tid & 63, wv = tid >> 6;
    int fr = lane & 15, quad = lane >> 4;
    __shared__ __align__(16) char smem_raw[12288];
    u16* Al = (u16*)smem_raw;            // [48][40] bf16
    u16* Bl = Al + 48 * 40;              // [64][40] bf16
    u16* Cst = (u16*)smem_raw;           // epilogue [48][64] bf16
    const float* Wn = Wt_g + ((size_t)n * P_ + (size_t)ph * 48) * L_;
    const u16* Tn = TRT + (size_t)n * (B_ * L_);
    floatx4 acc[3];
#pragma unroll
    for (int j = 0; j < 3; ++j) acc[j] = (floatx4){0.f, 0.f, 0.f, 0.f};
    float4 wr[2];
    uint4 br;

    auto fetch = [&](int c) {
        int k0 = c * 32, cur = L_ - k0;
#pragma unroll
        for (int t = 0; t < 2; ++t) {
            int u = tid + t * 256;                // W: 48*8 = 384 float4
            wr[t] = make_float4(0.f, 0.f, 0.f, 0.f);
            if (u < 384) {
                int row = u >> 3, c4 = (u & 7) * 4;
                if (c4 < cur) wr[t] = *(const float4*)&Wn[(size_t)row * L_ + k0 + c4];
            }
        }
        int brow = tid >> 2, c8 = (tid & 3) * 8;  // B: 64*4 = 256 uint4
        br = (c8 < cur) ? *(const uint4*)&Tn[(size_t)brow * L_ + k0 + c8]
                        : make_uint4(0u, 0u, 0u, 0u);
    };
    auto stage = [&]() {
#pragma unroll
        for (int t = 0; t < 2; ++t) {
            int u = tid + t * 256;
            if (u < 384) {
                int row = u >> 3, c4 = (u & 7) * 4;
                ushort4 pk;
                pk.x = f2bf(wr[t].x); pk.y = f2bf(wr[t].y);
                pk.z = f2bf(wr[t].z); pk.w = f2bf(wr[t].w);
                *(ushort4*)&Al[row * 40 + c4] = pk;
            }
        }
        int brow = tid >> 2, c8 = (tid & 3) * 8;
        *(uint4*)&Bl[brow * 40 + c8] = br;
    };
    auto compute = [&]() {
        bf16x8 bfr = *(const bf16x8*)&Bl[(wv * 16 + fr) * 40 + quad * 8];
#pragma unroll
        for (int j = 0; j < 3; ++j) {
            bf16x8 afr = *(const bf16x8*)&Al[(j * 16 + fr) * 40 + quad * 8];
            acc[j] = MFMA16(afr, bfr, acc[j]);
        }
    };

    fetch(0); stage();
    for (int c = 1; c < 16; ++c) {
        fetch(c);
        __syncthreads();
        compute();
        __syncthreads();
        stage();
    }
    __syncthreads();
    compute();

    __syncthreads();
#pragma unroll
    for (int j = 0; j < 3; ++j)
#pragma unroll
        for (int r = 0; r < 4; ++r) {
            int p = j * 16 + quad * 4 + r;
            float bias = bt[(size_t)(ph * 48 + p) * N_ + n];
            Cst[p * 64 + wv * 16 + fr] = f2bf(acc[j][r] + bias);
        }
    __syncthreads();
    u16* dstp = part + (size_t)n * PB_ + (size_t)ph * 48 * B_;
    for (int u = tid; u < 384; u += 256)          // 3072 u16 = 384 uint4
        *(uint4*)&dstp[u * 8] = *(const uint4*)&Cst[u * 8];
}

// ------- Kernel 3: transpose bf16 partial[n][p][b] -> fp32 out0 [b][p][n] --
__global__ __launch_bounds__(256) void k_reduce_trend(const u16* __restrict__ part,
                                                      float* __restrict__ out0) {
    int nt = blockIdx.x, p = blockIdx.y, tid = threadIdx.x;
    __shared__ float t[32][65];
    int n0 = nt * 32;
    for (int idx = tid; idx < 512; idx += 256) {
        int i = idx >> 4, j4 = (idx & 15) * 4;
        ushort4 v = *(const ushort4*)&part[(size_t)(n0 + i) * PB_ + p * 64 + j4];
        t[i][j4 + 0] = bf2f(v.x); t[i][j4 + 1] = bf2f(v.y);
        t[i][j4 + 2] = bf2f(v.z); t[i][j4 + 3] = bf2f(v.w);
    }
    __syncthreads();
    for (int idx = tid; idx < 2048; idx += 256) {
        int bb = idx >> 5, nl = idx & 31;
        out0[((size_t)bb * P_ + p) * N_ + n0 + nl] = t[nl][bb];
    }
}

// ------- Kernel 4: MERGED season + mid raw scores, embeds in-kernel. ------
// grid (B, 8 k-tiles of 64). The 64x64 ET time2vec tile is computed ONCE
// and serves both score sets. fp32 VALU (scores O(2500), exp-sensitive).
// (Round-10 structure: 6x4 register tile per thread — do NOT fuse softmax
// here; round 11's full-row fusion degraded the tile to 3x1 and cost 5x.)
__global__ __launch_bounds__(256) void k_scores(const float* __restrict__ T,
                                                const float* __restrict__ w0,
                                                const float* __restrict__ b0,
                                                const float* __restrict__ Wp,
                                                const float* __restrict__ Bp,
                                                float* __restrict__ WSE,
                                                float* __restrict__ WM_g) {
    int b = blockIdx.x, kt = blockIdx.y, tid = threadIdx.x;
    float* W = WSE + (size_t)b * P_ * L_;
    float* WM = WM_g + (size_t)b * MID_ * L_;
    __shared__ float Al[96][68];
    __shared__ float qv[7][68];
    __shared__ float Bl[64][68];
    float w0v = w0[0], b0v = b0[0];
    float Tlast = T[(size_t)b * S_ + (S_ - 1)];
    for (int idx = tid; idx < 96 * 64; idx += 256) {   // EN rows (T_next)
        int q = idx >> 6, d = idx & 63;
        Al[q][d] = t2v(Tlast + (float)(q + 1), d, w0v, b0v, Wp, Bp);
    }
    for (int idx = tid; idx < 7 * 64; idx += 256) {    // mid queries
        int q = idx >> 6, d = idx & 63;
        float t = T[(size_t)b * S_ + WIN_ + (L_ - MID_ + q)];
        qv[q][d] = t2v(t, d, w0v, b0v, Wp, Bp);
    }
    int k0 = kt * 64;
    for (int idx = tid; idx < 64 * 64; idx += 256) {   // ET tile (shared!)
        int kk = idx >> 6, d = idx & 63;
        int k = k0 + kk;
        float v = 0.f;
        if (k < L_) v = t2v(T[(size_t)b * S_ + WIN_ + k], d, w0v, b0v, Wp, Bp);
        Bl[kk][d] = v;
    }
    __syncthreads();
    // ---- season scores: C[96 q][64 k] ----
    {
        int qt = tid >> 4, ktl = tid & 15;
        float acc[6][4] = {};
        for (int d = 0; d < 64; d += 4) {
            float4 av[6], bv[4];
#pragma unroll
            for (int j = 0; j < 6; ++j) av[j] = *(const float4*)&Al[qt + 16 * j][d];
#pragma unroll
            for (int i = 0; i < 4; ++i) bv[i] = *(const float4*)&Bl[ktl + 16 * i][d];
#pragma unroll
            for (int j = 0; j < 6; ++j)
#pragma unroll
                for (int i = 0; i < 4; ++i)
                    acc[j][i] += av[j].x * bv[i].x + av[j].y * bv[i].y +
                                 av[j].z * bv[i].z + av[j].w * bv[i].w;
        }
#pragma unroll
        for (int j = 0; j < 6; ++j) {
            int q = qt + 16 * j;
#pragma unroll
            for (int i = 0; i < 4; ++i) {
                int k = k0 + ktl + 16 * i;
                if (k < L_) W[(size_t)q * L_ + k] = acc[j][i] * 0.125f;
            }
        }
    }
    // ---- mid masked scores: 7 q rows over the same ET tile ----
    {
        int klane = tid & 63, qs = tid >> 6;
        int q0 = qs, q1 = qs + 4;
        float a0 = 0.f, a1 = 0.f;
        for (int d = 0; d < 64; ++d) {
            float e = Bl[klane][d];
            a0 += e * qv[q0][d];
            if (q1 < 7) a1 += e * qv[q1][d];
        }
        int k = k0 + klane;
        if (k < L_) {
            WM[(size_t)q0 * L_ + k] = (k < L_ - MID_ + q0) ? a0 * 0.125f : -FLT_MAX;
            if (q1 < 7)
                WM[(size_t)q1 * L_ + k] = (k < L_ - MID_ + q1) ? a1 * 0.125f : -FLT_MAX;
        }
    }
}

// ------- Kernel 5: softmax rows fp32 -> bf16 weights (season) -------------
__global__ __launch_bounds__(64) void k_softmax_se(const float* __restrict__ WSE,
                                                   u16* __restrict__ WSEB) {
    size_t row = blockIdx.x;
    const float* base = WSE + row * L_;
    u16* out = WSEB + row * L_;
    int lane = threadIdx.x;
    float v[8];
    float m = -FLT_MAX;
#pragma unroll
    for (int i = 0; i < 8; ++i) {
        int idx = i * 64 + lane;
        v[i] = (idx < L_) ? base[idx] : -FLT_MAX;
        m = fmaxf(m, v[i]);
    }
    for (int off = 32; off; off >>= 1) m = fmaxf(m, __shfl_xor(m, off));
    float s = 0.f;
#pragma unroll
    for (int i = 0; i < 8; ++i) {
        float e = expf(v[i] - m);
        v[i] = e; s += e;
    }
    for (int off = 32; off; off >>= 1) s += __shfl_xor(s, off);
    float inv = 1.f / s;
#pragma unroll
    for (int i = 0; i < 8; ++i) {
        int idx = i * 64 + lane;
        if (idx < L_) out[idx] = f2bf(v[i] * inv);
    }
}

// ------- Kernel 6: softmax rows fp32 -> bf16 weights (mid) ----------------
__global__ __launch_bounds__(64) void k_softmax_mid(const float* __restrict__ WM_g,
                                                    u16* __restrict__ WMB) {
    size_t row = blockIdx.x;
    const float* base = WM_g + row * L_;
    u16* out = WMB + row * L_;
    int lane = threadIdx.x;
    float v[8];
    float m = -FLT_MAX;
#pragma unroll
    for (int i = 0; i < 8; ++i) {
        int idx = i * 64 + lane;
        v[i] = (idx < L_) ? base[idx] : -FLT_MAX;
        m = fmaxf(m, v[i]);
    }
    for (int off = 32; off; off >>= 1) m = fmaxf(m, __shfl_xor(m, off));
    float s = 0.f;
#pragma unroll
    for (int i = 0; i < 8; ++i) {
        float e = expf(v[i] - m);
        v[i] = e; s += e;
    }
    for (int off = 32; off; off >>= 1) s += __shfl_xor(s, off);
    float inv = 1.f / s;
#pragma unroll
    for (int i = 0; i < 8; ++i) {
        int idx = i * 64 + lane;
        if (idx < L_) out[idx] = f2bf(v[i] * inv);
    }
}

// ------- Kernel 7: season PV via MFMA, q-split x2. grid (B, 4, 2). --------
__global__ __launch_bounds__(256) void k_season_pv(const u16* __restrict__ WSEB,
                                                   const u16* __restrict__ XST,
                                                   float* __restrict__ out0) {
    int b = blockIdx.x, nt = blockIdx.y, qh = blockIdx.z, tid = threadIdx.x;
    int lane = tid & 63, wv = tid >> 6;
    int fr = lane & 15, quad = lane >> 4;
    __shared__ __align__(16) char smem_raw[12288];
    u16* Al = (u16*)smem_raw;            // Wse [48][40]
    u16* Bl = Al + 48 * 40;              // XsT [64][40]
    float* Cst = (float*)smem_raw;       // [48][64]
    const u16* Wa = WSEB + ((size_t)b * P_ + (size_t)qh * 48) * L_;
    const u16* Xb = XST + ((size_t)b * N_ + nt * 64) * L_;
    floatx4 acc[3];
#pragma unroll
    for (int j = 0; j < 3; ++j) acc[j] = (floatx4){0.f, 0.f, 0.f, 0.f};
    uint4 ar, br;

    auto fetch = [&](int c) {
        int k0 = c * 32, cur = L_ - k0;
        ar = make_uint4(0u, 0u, 0u, 0u);
        if (tid < 192) {
            int row = tid >> 2, c8 = (tid & 3) * 8;
            if (c8 < cur) ar = *(const uint4*)&Wa[(size_t)row * L_ + k0 + c8];
        }
        int brow = tid >> 2, c8 = (tid & 3) * 8;
        br = (c8 < cur) ? *(const uint4*)&Xb[(size_t)brow * L_ + k0 + c8]
                        : make_uint4(0u, 0u, 0u, 0u);
    };
    auto stage = [&]() {
        if (tid < 192) {
            int row = tid >> 2, c8 = (tid & 3) * 8;
            *(uint4*)&Al[row * 40 + c8] = ar;
        }
        int brow = tid >> 2, c8 = (tid & 3) * 8;
        *(uint4*)&Bl[brow * 40 + c8] = br;
    };
    auto compute = [&]() {
        bf16x8 bfr = *(const bf16x8*)&Bl[(wv * 16 + fr) * 40 + quad * 8];
#pragma unroll
        for (int j = 0; j < 3; ++j) {
            bf16x8 afr = *(const bf16x8*)&Al[(j * 16 + fr) * 40 + quad * 8];
            acc[j] = MFMA16(afr, bfr, acc[j]);
        }
    };

    fetch(0); stage();
    for (int c = 1; c < 16; ++c) {
        fetch(c);
        __syncthreads();
        compute();
        __syncthreads();
        stage();
    }
    __syncthreads();
    compute();

    __syncthreads();
#pragma unroll
    for (int j = 0; j < 3; ++j)
#pragma unroll
        for (int r = 0; r < 4; ++r)
            Cst[(j * 16 + quad * 4 + r) * 64 + wv * 16 + fr] = acc[j][r];
    __syncthreads();
    float* o = out0 + (size_t)b * P_ * N_ + nt * 64;
    for (int u = tid; u < 768; u += 256) {
        int pl = u >> 4, c4 = (u & 15) * 4;
        float4* op = (float4*)&o[(size_t)(qh * 48 + pl) * N_ + c4];
        float4 pv = *op;
        const float* cs = &Cst[pl * 64 + c4];
        pv.x += cs[0]; pv.y += cs[1]; pv.z += cs[2]; pv.w += cs[3];
        *op = pv;
    }
}

// ------- Kernel 8: mid PV from XsT + bf16 weights. grid (B, 8), block 256 --
// Per-lane sequential XsT rows (976 B each; 32 rows/block = L1-resident).
__global__ __launch_bounds__(256) void k_mid_pv(const u16* __restrict__ XST,
                                                const u16* __restrict__ WMB,
                                                float* __restrict__ out1) {
    int b = blockIdx.x, nt = blockIdx.y, tid = threadIdx.x;
    int nl = tid & 31, ks = tid >> 5;   // 8 k-slices of 61
    __shared__ float wl[7 * L_];
    __shared__ float part[8][7][33];
    const u16* WMb = WMB + (size_t)b * MID_ * L_;
    for (int idx = tid; idx < 7 * L_; idx += 256) wl[idx] = bf2f(WMb[idx]);
    __syncthreads();
    const u16* xrow = XST + ((size_t)b * N_ + nt * 32 + nl) * L_;
    float acc[7] = {};
    int kbeg = ks * 61, kend = kbeg + 61;
    for (int k = kbeg; k < kend; ++k) {
        float xv = bf2f(xrow[k]);
#pragma unroll
        for (int q = 0; q < 7; ++q) acc[q] += wl[q * L_ + k] * xv;
    }
#pragma unroll
    for (int q = 0; q < 7; ++q) part[ks][q][nl] = acc[q];
    __syncthreads();
    if (ks == 0) {
#pragma unroll
        for (int q = 0; q < 7; ++q) {
            float v = 0.f;
#pragma unroll
            for (int s = 0; s < 8; ++s) v += part[s][q][nl];
            out1[((size_t)b * MID_ + q) * N_ + nt * 32 + nl] = v;
        }
    }
}

extern "C" void kernel_launch(void* const* d_in, const int* in_sizes, int n_in,
                              void* d_out, int out_size, void* d_ws, size_t ws_size,
                              hipStream_t stream) {
    (void)in_sizes; (void)n_in; (void)out_size; (void)ws_size;
    const float* X  = (const float*)d_in[0];
    const float* T  = (const float*)d_in[1];
    const float* Wt = (const float*)d_in[2];
    const float* bt = (const float*)d_in[3];
    const float* w0 = (const float*)d_in[4];
    const float* b0 = (const float*)d_in[5];
    const float* Wp = (const float*)d_in[6];
    const float* Bp = (const float*)d_in[7];
    float* out = (float*)d_out;
    char* w8 = (char*)d_ws;
    float* out1 = out + (size_t)B_ * P_ * N_;

    u16*   XST  = (u16*)(w8 + OFF_XST);
    u16*   TRT  = (u16*)(w8 + OFF_TRT);
    float* WSE  = (float*)(w8 + OFF_WSE);
    u16*   WSEB = (u16*)(w8 + OFF_WSEB);
    float* WM   = (float*)(w8 + OFF_WM);
    u16*   WMB  = (u16*)(w8 + OFF_WM + (size_t)B_ * MID_ * L_ * 4);  // after fp32 WM
    u16*   PART = (u16*)(w8 + OFF_PART);

    hipLaunchKernelGGL(k_trend, dim3(B_, 16), dim3(256), 0, stream, X, XST, TRT);
    hipLaunchKernelGGL(k_trend_gemm, dim3(N_, 2), dim3(256), 0, stream, Wt, bt, TRT, PART);
    hipLaunchKernelGGL(k_reduce_trend, dim3(8, 96), dim3(256), 0, stream, PART, out);
    hipLaunchKernelGGL(k_scores, dim3(B_, 8), dim3(256), 0, stream,
                       T, w0, b0, Wp, Bp, WSE, WM);
    hipLaunchKernelGGL(k_softmax_se, dim3(B_ * P_), dim3(64), 0, stream, WSE, WSEB);
    hipLaunchKernelGGL(k_softmax_mid, dim3(B_ * MID_), dim3(64), 0, stream, WM, WMB);
    hipLaunchKernelGGL(k_season_pv, dim3(B_, 4, 2), dim3(256), 0, stream, WSEB, XST, out);
    hipLaunchKernelGGL(k_mid_pv, dim3(B_, 8), dim3(256), 0, stream, XST, WMB, out1);
}

// Round 13
// 183.925 us; speedup vs baseline: 1.4249x; 1.0811x over previous
//
#include <hip/hip_runtime.h>
#include <math.h>
#include <float.h>

#define B_ 64
#define S_ 512
#define N_ 256
#define P_ 96
#define D_ 64
#define WIN_ 24
#define L_ 488   // S_ - WIN_
#define MID_ 7
#define PB_ (P_*B_)   // 6144

typedef unsigned short u16;
typedef __attribute__((ext_vector_type(4))) float floatx4;
typedef __attribute__((ext_vector_type(8))) short bf16x8;
#define MFMA16(a,b,c) __builtin_amdgcn_mfma_f32_16x16x32_bf16(a,b,c,0,0,0)

// workspace layout (BYTE offsets) — NO aliasing: trend_gemm and k_scores
// now share one dispatch, so PART must not overlap WSE.
#define OFF_XST  ((size_t)0)                 // XsT bf16 [B][N][L]  15,990,784
#define OFF_TRT  ((size_t)15990784)          // trT bf16 [N][B][L]  15,990,784
#define OFF_WSE  ((size_t)31981568)          // season scores fp32 [B][P][L] 11,993,088
#define OFF_WSEB ((size_t)43974656)          // season weights bf16 [B][P][L] 5,996,544
#define OFF_WM   ((size_t)49971200)          // mid scores fp32 [B][MID][L] 874,496
#define OFF_WMB  ((size_t)50845696)          // mid weights bf16 437,248
#define OFF_PART ((size_t)51282944)          // trend partials bf16 [N][P][B] 3,145,728

__device__ inline u16 f2bf(float f) {
    union { float f; unsigned u; } v; v.f = f;
    unsigned r = v.u + 0x7FFFu + ((v.u >> 16) & 1u);
    return (u16)(r >> 16);
}
__device__ inline float bf2f(u16 u) {
    union { unsigned u; float f; } v; v.u = ((unsigned)u) << 16;
    return v.f;
}
// time2vec element d of embed at time t (d==0 linear, else sin)
__device__ inline float t2v(float t, int d, float w0v, float b0v,
                            const float* __restrict__ Wp,
                            const float* __restrict__ Bp) {
    return (d == 0) ? (t * w0v + b0v) : sinf(t * Wp[d - 1] + Bp[d - 1]);
}

// ---------------- Kernel 1: rolling-mean trend + season ----------------
// grid (B, 16 l-tiles of 32), block 256 (thread = n). Emits XsT [B][N][L]
// and trT [N][B][L] via LDS transpose.
__global__ __launch_bounds__(256) void k_trend(const float* __restrict__ X,
                                               u16* __restrict__ XST,
                                               u16* __restrict__ TRT) {
    int b = blockIdx.x, tile = blockIdx.y, n = threadIdx.x;
    __shared__ u16 tr_tile[256][34];
    __shared__ u16 xs_tile[256][34];
    const float* Xb = X + (size_t)b * S_ * N_ + n;
    int l0 = tile * 32;
    int cur = L_ - l0; if (cur > 32) cur = 32;    // 32 or 8 (tail)
    int s1 = WIN_ + l0;
    float wsum = 0.f;
    for (int s = s1 - WIN_; s < s1; ++s) wsum += Xb[(size_t)s * N_];
    for (int i = 0; i < cur; ++i) {
        int s = s1 + i;
        float xv = Xb[(size_t)s * N_];
        wsum += xv - Xb[(size_t)(s - WIN_) * N_];
        float tr = wsum * (1.f / WIN_);
        tr_tile[n][i] = f2bf(tr);
        xs_tile[n][i] = f2bf(xv - tr);
    }
    __syncthreads();
    int wv = threadIdx.x >> 6, lane = threadIdx.x & 63;
    int half = lane >> 5, c = lane & 31;          // 2 rows per instruction
    if (c < cur) {
        for (int it = 0; it < 32; ++it) {
            int r = it * 8 + wv * 2 + half;
            TRT[(size_t)r * (B_ * L_) + (size_t)b * L_ + l0 + c] = tr_tile[r][c];
            XST[((size_t)b * N_ + r) * L_ + l0 + c] = xs_tile[r][c];
        }
    }
}

// ------- Kernel 2 (MERGED dispatch): trend GEMM  |  scores ----------------
// flat grid.x = 512 (gemm: n*2+ph) + 512 (scores: b*8+kt). Bodies identical
// to the proven standalone kernels; shared raw LDS buffer sized to max.
__global__ __launch_bounds__(256) void k_gemm_scores(const float* __restrict__ Wt_g,
                                                     const float* __restrict__ bt,
                                                     const u16* __restrict__ TRT,
                                                     u16* __restrict__ part,
                                                     const float* __restrict__ T,
                                                     const float* __restrict__ w0,
                                                     const float* __restrict__ b0,
                                                     const float* __restrict__ Wp,
                                                     const float* __restrict__ Bp,
                                                     float* __restrict__ WSE,
                                                     float* __restrict__ WM_g) {
    __shared__ __align__(16) char smem_raw[45424];   // max(12288 gemm, 45424 scores)
    int bid = blockIdx.x, tid = threadIdx.x;
    if (bid < 512) {
        // ================= trend GEMM via MFMA, p-split x2 ================
        int n = bid >> 1, ph = bid & 1;
        int lane = tid & 63, wv = tid >> 6;
        int fr = lane & 15, quad = lane >> 4;
        u16* Al = (u16*)smem_raw;            // [48][40] bf16
        u16* Bl = Al + 48 * 40;              // [64][40] bf16
        u16* Cst = (u16*)smem_raw;           // epilogue [48][64] bf16
        const float* Wn = Wt_g + ((size_t)n * P_ + (size_t)ph * 48) * L_;
        const u16* Tn = TRT + (size_t)n * (B_ * L_);
        floatx4 acc[3];
#pragma unroll
        for (int j = 0; j < 3; ++j) acc[j] = (floatx4){0.f, 0.f, 0.f, 0.f};
        float4 wr[2];
        uint4 br;

        auto fetch = [&](int c) {
            int k0 = c * 32, cur = L_ - k0;
#pragma unroll
            for (int t = 0; t < 2; ++t) {
                int u = tid + t * 256;            // W: 48*8 = 384 float4
                wr[t] = make_float4(0.f, 0.f, 0.f, 0.f);
                if (u < 384) {
                    int row = u >> 3, c4 = (u & 7) * 4;
                    if (c4 < cur) wr[t] = *(const float4*)&Wn[(size_t)row * L_ + k0 + c4];
                }
            }
            int brow = tid >> 2, c8 = (tid & 3) * 8;
            br = (c8 < cur) ? *(const uint4*)&Tn[(size_t)brow * L_ + k0 + c8]
                            : make_uint4(0u, 0u, 0u, 0u);
        };
        auto stage = [&]() {
#pragma unroll
            for (int t = 0; t < 2; ++t) {
                int u = tid + t * 256;
                if (u < 384) {
                    int row = u >> 3, c4 = (u & 7) * 4;
                    ushort4 pk;
                    pk.x = f2bf(wr[t].x); pk.y = f2bf(wr[t].y);
                    pk.z = f2bf(wr[t].z); pk.w = f2bf(wr[t].w);
                    *(ushort4*)&Al[row * 40 + c4] = pk;
                }
            }
            int brow = tid >> 2, c8 = (tid & 3) * 8;
            *(uint4*)&Bl[brow * 40 + c8] = br;
        };
        auto compute = [&]() {
            bf16x8 bfr = *(const bf16x8*)&Bl[(wv * 16 + fr) * 40 + quad * 8];
#pragma unroll
            for (int j = 0; j < 3; ++j) {
                bf16x8 afr = *(const bf16x8*)&Al[(j * 16 + fr) * 40 + quad * 8];
                acc[j] = MFMA16(afr, bfr, acc[j]);
            }
        };

        fetch(0); stage();
        for (int c = 1; c < 16; ++c) {
            fetch(c);
            __syncthreads();
            compute();
            __syncthreads();
            stage();
        }
        __syncthreads();
        compute();

        __syncthreads();
#pragma unroll
        for (int j = 0; j < 3; ++j)
#pragma unroll
            for (int r = 0; r < 4; ++r) {
                int p = j * 16 + quad * 4 + r;
                float bias = bt[(size_t)(ph * 48 + p) * N_ + n];
                Cst[p * 64 + wv * 16 + fr] = f2bf(acc[j][r] + bias);
            }
        __syncthreads();
        u16* dstp = part + (size_t)n * PB_ + (size_t)ph * 48 * B_;
        for (int u = tid; u < 384; u += 256)
            *(uint4*)&dstp[u * 8] = *(const uint4*)&Cst[u * 8];
    } else {
        // ============ merged season + mid raw scores (round-10) ===========
        int r = bid - 512;
        int b = r >> 3, kt = r & 7;
        float* W = WSE + (size_t)b * P_ * L_;
        float* WM = WM_g + (size_t)b * MID_ * L_;
        float* Al = (float*)smem_raw;            // [96][68]
        float* qv = Al + 96 * 68;                // [7][68]
        float* Bl = qv + 7 * 68;                 // [64][68]
        float w0v = w0[0], b0v = b0[0];
        float Tlast = T[(size_t)b * S_ + (S_ - 1)];
        for (int idx = tid; idx < 96 * 64; idx += 256) {
            int q = idx >> 6, d = idx & 63;
            Al[q * 68 + d] = t2v(Tlast + (float)(q + 1), d, w0v, b0v, Wp, Bp);
        }
        for (int idx = tid; idx < 7 * 64; idx += 256) {
            int q = idx >> 6, d = idx & 63;
            float t = T[(size_t)b * S_ + WIN_ + (L_ - MID_ + q)];
            qv[q * 68 + d] = t2v(t, d, w0v, b0v, Wp, Bp);
        }
        int k0 = kt * 64;
        for (int idx = tid; idx < 64 * 64; idx += 256) {
            int kk = idx >> 6, d = idx & 63;
            int k = k0 + kk;
            float v = 0.f;
            if (k < L_) v = t2v(T[(size_t)b * S_ + WIN_ + k], d, w0v, b0v, Wp, Bp);
            Bl[kk * 68 + d] = v;
        }
        __syncthreads();
        {   // season scores: C[96 q][64 k], 6x4 register tile
            int qt = tid >> 4, ktl = tid & 15;
            float acc[6][4] = {};
            for (int d = 0; d < 64; d += 4) {
                float4 av[6], bv[4];
#pragma unroll
                for (int j = 0; j < 6; ++j) av[j] = *(const float4*)&Al[(qt + 16 * j) * 68 + d];
#pragma unroll
                for (int i = 0; i < 4; ++i) bv[i] = *(const float4*)&Bl[(ktl + 16 * i) * 68 + d];
#pragma unroll
                for (int j = 0; j < 6; ++j)
#pragma unroll
                    for (int i = 0; i < 4; ++i)
                        acc[j][i] += av[j].x * bv[i].x + av[j].y * bv[i].y +
                                     av[j].z * bv[i].z + av[j].w * bv[i].w;
            }
#pragma unroll
            for (int j = 0; j < 6; ++j) {
                int q = qt + 16 * j;
#pragma unroll
                for (int i = 0; i < 4; ++i) {
                    int k = k0 + ktl + 16 * i;
                    if (k < L_) W[(size_t)q * L_ + k] = acc[j][i] * 0.125f;
                }
            }
        }
        {   // mid masked scores over the same ET tile
            int klane = tid & 63, qs = tid >> 6;
            int q0 = qs, q1 = qs + 4;
            float a0 = 0.f, a1 = 0.f;
            for (int d = 0; d < 64; ++d) {
                float e = Bl[klane * 68 + d];
                a0 += e * qv[q0 * 68 + d];
                if (q1 < 7) a1 += e * qv[q1 * 68 + d];
            }
            int k = k0 + klane;
            if (k < L_) {
                WM[(size_t)q0 * L_ + k] = (k < L_ - MID_ + q0) ? a0 * 0.125f : -FLT_MAX;
                if (q1 < 7)
                    WM[(size_t)q1 * L_ + k] = (k < L_ - MID_ + q1) ? a1 * 0.125f : -FLT_MAX;
            }
        }
    }
}

// ------- Kernel 3 (MERGED dispatch): reduce_trend | softmax se+mid --------
// flat grid.x = 768 (reduce: nt=bid&7, p=bid>>3) + 1648 (softmax: 4 rows
// per block, one per wave; rows 0..6143 season, 6144..6591 mid).
__global__ __launch_bounds__(256) void k_reduce_softmax(const u16* __restrict__ part,
                                                        float* __restrict__ out0,
                                                        const float* __restrict__ WSE,
                                                        u16* __restrict__ WSEB,
                                                        const float* __restrict__ WM_g,
                                                        u16* __restrict__ WMB) {
    __shared__ __align__(16) char smem_raw[8320];
    int bid = blockIdx.x, tid = threadIdx.x;
    if (bid < 768) {
        // transpose bf16 partial[n][p][b] -> fp32 out0 [b][p][n]
        int nt = bid & 7, p = bid >> 3;
        float* t = (float*)smem_raw;             // [32][65]
        int n0 = nt * 32;
        for (int idx = tid; idx < 512; idx += 256) {
            int i = idx >> 4, j4 = (idx & 15) * 4;
            ushort4 v = *(const ushort4*)&part[(size_t)(n0 + i) * PB_ + p * 64 + j4];
            t[i * 65 + j4 + 0] = bf2f(v.x); t[i * 65 + j4 + 1] = bf2f(v.y);
            t[i * 65 + j4 + 2] = bf2f(v.z); t[i * 65 + j4 + 3] = bf2f(v.w);
        }
        __syncthreads();
        for (int idx = tid; idx < 2048; idx += 256) {
            int bb = idx >> 5, nl = idx & 31;
            out0[((size_t)bb * P_ + p) * N_ + n0 + nl] = t[nl * 65 + bb];
        }
    } else {
        int row = (bid - 768) * 4 + (tid >> 6);  // 6592 rows total
        int lane = tid & 63;
        const float* base;
        u16* out;
        if (row < 6144) {
            base = WSE + (size_t)row * L_;
            out = WSEB + (size_t)row * L_;
        } else {
            base = WM_g + (size_t)(row - 6144) * L_;
            out = WMB + (size_t)(row - 6144) * L_;
        }
        float v[8], m = -FLT_MAX;
#pragma unroll
        for (int i = 0; i < 8; ++i) {
            int idx = i * 64 + lane;
            v[i] = (idx < L_) ? base[idx] : -FLT_MAX;
            m = fmaxf(m, v[i]);
        }
        for (int off = 32; off; off >>= 1) m = fmaxf(m, __shfl_xor(m, off));
        float s = 0.f;
#pragma unroll
        for (int i = 0; i < 8; ++i) { float e = expf(v[i] - m); v[i] = e; s += e; }
        for (int off = 32; off; off >>= 1) s += __shfl_xor(s, off);
        float inv = 1.f / s;
#pragma unroll
        for (int i = 0; i < 8; ++i) {
            int idx = i * 64 + lane;
            if (idx < L_) out[idx] = f2bf(v[i] * inv);
        }
    }
}

// ------- Kernel 4 (MERGED dispatch): season PV | mid PV -------------------
// grid (B, 16): y<8 -> season (nt=y>>1, qh=y&1); y>=8 -> mid (nt=y-8).
__global__ __launch_bounds__(256) void k_pv(const u16* __restrict__ WSEB,
                                            const u16* __restrict__ XST,
                                            float* __restrict__ out0,
                                            const u16* __restrict__ WMB,
                                            float* __restrict__ out1) {
    __shared__ __align__(16) char smem_raw[21056];   // max(12288 season, 21056 mid)
    int b = blockIdx.x, y = blockIdx.y, tid = threadIdx.x;
    if (y < 8) {
        // ============== season PV via MFMA, q-split x2 ====================
        int nt = y >> 1, qh = y & 1;
        int lane = tid & 63, wv = tid >> 6;
        int fr = lane & 15, quad = lane >> 4;
        u16* Al = (u16*)smem_raw;            // Wse [48][40]
        u16* Bl = Al + 48 * 40;              // XsT [64][40]
        float* Cst = (float*)smem_raw;       // [48][64]
        const u16* Wa = WSEB + ((size_t)b * P_ + (size_t)qh * 48) * L_;
        const u16* Xb = XST + ((size_t)b * N_ + nt * 64) * L_;
        floatx4 acc[3];
#pragma unroll
        for (int j = 0; j < 3; ++j) acc[j] = (floatx4){0.f, 0.f, 0.f, 0.f};
        uint4 ar, br;

        auto fetch = [&](int c) {
            int k0 = c * 32, cur = L_ - k0;
            ar = make_uint4(0u, 0u, 0u, 0u);
            if (tid < 192) {
                int row = tid >> 2, c8 = (tid & 3) * 8;
                if (c8 < cur) ar = *(const uint4*)&Wa[(size_t)row * L_ + k0 + c8];
            }
            int brow = tid >> 2, c8 = (tid & 3) * 8;
            br = (c8 < cur) ? *(const uint4*)&Xb[(size_t)brow * L_ + k0 + c8]
                            : make_uint4(0u, 0u, 0u, 0u);
        };
        auto stage = [&]() {
            if (tid < 192) {
                int row = tid >> 2, c8 = (tid & 3) * 8;
                *(uint4*)&Al[row * 40 + c8] = ar;
            }
            int brow = tid >> 2, c8 = (tid & 3) * 8;
            *(uint4*)&Bl[brow * 40 + c8] = br;
        };
        auto compute = [&]() {
            bf16x8 bfr = *(const bf16x8*)&Bl[(wv * 16 + fr) * 40 + quad * 8];
#pragma unroll
            for (int j = 0; j < 3; ++j) {
                bf16x8 afr = *(const bf16x8*)&Al[(j * 16 + fr) * 40 + quad * 8];
                acc[j] = MFMA16(afr, bfr, acc[j]);
            }
        };

        fetch(0); stage();
        for (int c = 1; c < 16; ++c) {
            fetch(c);
            __syncthreads();
            compute();
            __syncthreads();
            stage();
        }
        __syncthreads();
        compute();

        __syncthreads();
#pragma unroll
        for (int j = 0; j < 3; ++j)
#pragma unroll
            for (int r = 0; r < 4; ++r)
                Cst[(j * 16 + quad * 4 + r) * 64 + wv * 16 + fr] = acc[j][r];
        __syncthreads();
        float* o = out0 + (size_t)b * P_ * N_ + nt * 64;
        for (int u = tid; u < 768; u += 256) {
            int pl = u >> 4, c4 = (u & 15) * 4;
            float4* op = (float4*)&o[(size_t)(qh * 48 + pl) * N_ + c4];
            float4 pv = *op;
            const float* cs = &Cst[pl * 64 + c4];
            pv.x += cs[0]; pv.y += cs[1]; pv.z += cs[2]; pv.w += cs[3];
            *op = pv;
        }
    } else {
        // ================ mid PV from XsT + bf16 weights ==================
        int nt = y - 8;
        int nl = tid & 31, ks = tid >> 5;        // 8 k-slices of 61
        float* wl = (float*)smem_raw;            // [7*L_] = 13,664 B
        float* partl = (float*)(smem_raw + 13664); // [8][7][33] = 7,392 B
        const u16* WMb = WMB + (size_t)b * MID_ * L_;
        for (int idx = tid; idx < 7 * L_; idx += 256) wl[idx] = bf2f(WMb[idx]);
        __syncthreads();
        const u16* xrow = XST + ((size_t)b * N_ + nt * 32 + nl) * L_;
        float acc[7] = {};
        int kbeg = ks * 61, kend = kbeg + 61;
        for (int k = kbeg; k < kend; ++k) {
            float xv = bf2f(xrow[k]);
#pragma unroll
            for (int q = 0; q < 7; ++q) acc[q] += wl[q * L_ + k] * xv;
        }
#pragma unroll
        for (int q = 0; q < 7; ++q) partl[(ks * 7 + q) * 33 + nl] = acc[q];
        __syncthreads();
        if (ks == 0) {
#pragma unroll
            for (int q = 0; q < 7; ++q) {
                float v = 0.f;
#pragma unroll
                for (int s = 0; s < 8; ++s) v += partl[(s * 7 + q) * 33 + nl];
                out1[((size_t)b * MID_ + q) * N_ + nt * 32 + nl] = v;
            }
        }
    }
}

extern "C" void kernel_launch(void* const* d_in, const int* in_sizes, int n_in,
                              void* d_out, int out_size, void* d_ws, size_t ws_size,
                              hipStream_t stream) {
    (void)in_sizes; (void)n_in; (void)out_size; (void)ws_size;
    const float* X  = (const float*)d_in[0];
    const float* T  = (const float*)d_in[1];
    const float* Wt = (const float*)d_in[2];
    const float* bt = (const float*)d_in[3];
    const float* w0 = (const float*)d_in[4];
    const float* b0 = (const float*)d_in[5];
    const float* Wp = (const float*)d_in[6];
    const float* Bp = (const float*)d_in[7];
    float* out = (float*)d_out;
    char* w8 = (char*)d_ws;
    float* out1 = out + (size_t)B_ * P_ * N_;

    u16*   XST  = (u16*)(w8 + OFF_XST);
    u16*   TRT  = (u16*)(w8 + OFF_TRT);
    float* WSE  = (float*)(w8 + OFF_WSE);
    u16*   WSEB = (u16*)(w8 + OFF_WSEB);
    float* WM   = (float*)(w8 + OFF_WM);
    u16*   WMB  = (u16*)(w8 + OFF_WMB);
    u16*   PART = (u16*)(w8 + OFF_PART);

    hipLaunchKernelGGL(k_trend, dim3(B_, 16), dim3(256), 0, stream, X, XST, TRT);
    hipLaunchKernelGGL(k_gemm_scores, dim3(1024), dim3(256), 0, stream,
                       Wt, bt, TRT, PART, T, w0, b0, Wp, Bp, WSE, WM);
    hipLaunchKernelGGL(k_reduce_softmax, dim3(768 + 1648), dim3(256), 0, stream,
                       PART, out, WSE, WSEB, WM, WMB);
    hipLaunchKernelGGL(k_pv, dim3(B_, 16), dim3(256), 0, stream,
                       WSEB, XST, out, WMB, out1);
}